// Round 5
// baseline (123.614 us; speedup 1.0000x reference)
//
#include <hip/hip_runtime.h>
#include <hip/hip_fp16.h>

#define POOLED 7
#define PP 49
#define ROI_SCALE 0.25f
#define FH 200
#define FW 304
#define FHW 60800
#define FC 256

// ---------- Pass 1: NCHW fp32 -> NHWC fp16 ----------
__global__ __launch_bounds__(256) void transpose_f16(
    const float* __restrict__ in, __half* __restrict__ out)
{
    __shared__ float tile[64][33];
    const int b   = blockIdx.z;
    const int hw0 = blockIdx.x * 32;
    const int c0  = blockIdx.y * 64;
    const int tx  = threadIdx.x;   // 0..31
    const int ty  = threadIdx.y;   // 0..7

    #pragma unroll
    for (int i = 0; i < 8; i++) {
        int c = c0 + ty + i * 8;
        tile[ty + i * 8][tx] = in[((size_t)b * FC + c) * FHW + hw0 + tx];
    }
    __syncthreads();
    #pragma unroll
    for (int i = 0; i < 4; i++) {
        int hwl = ty + i * 8;
        __half2 h = __floats2half2_rn(tile[2 * tx][hwl], tile[2 * tx + 1][hwl]);
        *reinterpret_cast<__half2*>(
            out + ((size_t)b * FHW + hwl + hw0) * FC + c0 + 2 * tx) = h;
    }
}

// load 8 consecutive fp16 channels (16 B) and widen
__device__ __forceinline__ void ld8(const __half* p, float o[8]) {
    uint4 u = *reinterpret_cast<const uint4*>(p);
    const __half2* h = reinterpret_cast<const __half2*>(&u);
    #pragma unroll
    for (int j = 0; j < 4; j++) {
        float2 f = __half22float2(h[j]);
        o[2 * j]     = f.x;
        o[2 * j + 1] = f.y;
    }
}

// ---------- Pass 2: grid (N, 13). Block = 4 waves; wave w owns bin 4q+w.
// Lane owns 8 channels (16B). Half-wave split: lanes<32 load xlo pixels,
// lanes>=32 load xhi pixels -> 8 dwordx4 loads per bin, all independent.
__global__ __launch_bounds__(256) void roi_gather_f16(
    const __half* __restrict__ f,
    const float* __restrict__ rois,
    float* __restrict__ out)
{
    __shared__ float s_out[4][260];

    const int n    = blockIdx.x;
    const int q    = blockIdx.y;
    const int tid  = threadIdx.x;
    const int wave = tid >> 6;
    const int lane = tid & 63;
    const int hl   = lane & 31;
    const bool hiHalf = lane >= 32;

    const float* r = rois + (size_t)n * 5;
    const int   bi = (int)r[0];
    const float x1 = r[1] * ROI_SCALE;
    const float y1 = r[2] * ROI_SCALE;
    const float bin_w = fmaxf(r[3] * ROI_SCALE - x1, 1.0f) / (float)POOLED;
    const float bin_h = fmaxf(r[4] * ROI_SCALE - y1, 1.0f) / (float)POOLED;

    const int bin = min(4 * q + wave, 48);   // q=12 extra waves duplicate bin 48 (benign)
    const int ph = bin / 7;
    const int pw = bin - ph * 7;

    // y params for the bin's two y-samples
    int rowlo[2], rowhi[2];
    float why[2], wly[2];
    #pragma unroll
    for (int iy = 0; iy < 2; iy++) {
        float c = y1 + ((float)(2 * ph + iy) + 0.5f) * 0.5f * bin_h;
        float v = ((c >= -1.0f) && (c <= (float)FH)) ? 1.0f : 0.0f;
        c = fmaxf(c, 0.0f);
        int lo = (int)floorf(c);
        bool edge = (lo >= FH - 1);
        lo = min(lo, FH - 1);
        rowlo[iy] = lo * FW;
        rowhi[iy] = min(lo + 1, FH - 1) * FW;
        float ly = edge ? 0.0f : (c - (float)lo);
        why[iy] = v * (1.0f - ly);
        wly[iy] = v * ly;
    }
    // x params: per-lane select lo/hi pixel and matching weight
    int   xoff[2];
    float wx[2];
    #pragma unroll
    for (int ix = 0; ix < 2; ix++) {
        float c = x1 + ((float)(2 * pw + ix) + 0.5f) * 0.5f * bin_w;
        float v = ((c >= -1.0f) && (c <= (float)FW)) ? 1.0f : 0.0f;
        c = fmaxf(c, 0.0f);
        int lo = (int)floorf(c);
        bool edge = (lo >= FW - 1);
        lo = min(lo, FW - 1);
        int hi = min(lo + 1, FW - 1);
        float lx = edge ? 0.0f : (c - (float)lo);
        xoff[ix] = hiHalf ? hi : lo;
        wx[ix]   = v * (hiHalf ? lx : (1.0f - lx));
    }

    const __half* base = f + (size_t)bi * (FHW * FC) + 8 * hl;

    float acc[8] = {0.f, 0.f, 0.f, 0.f, 0.f, 0.f, 0.f, 0.f};
    #pragma unroll
    for (int iy = 0; iy < 2; iy++) {
        #pragma unroll
        for (int ix = 0; ix < 2; ix++) {
            float vlo[8], vhi[8];
            ld8(base + ((rowlo[iy] + xoff[ix]) << 8), vlo);
            ld8(base + ((rowhi[iy] + xoff[ix]) << 8), vhi);
            float wlo = why[iy] * wx[ix];
            float whi = wly[iy] * wx[ix];
            #pragma unroll
            for (int k = 0; k < 8; k++)
                acc[k] += wlo * vlo[k] + whi * vhi[k];
        }
    }

    // merge xlo/xhi halves: lane i += lane i^32
    #pragma unroll
    for (int k = 0; k < 8; k++)
        acc[k] += __shfl_xor(acc[k], 32, 64);

    const int bl = bin - 4 * q;
    if (!hiHalf) {
        #pragma unroll
        for (int k = 0; k < 8; k++)
            s_out[bl][8 * hl + k] = acc[k] * 0.25f;
    }
    __syncthreads();

    const int nb = min(49 - 4 * q, 4);
    float* ob = out + (size_t)n * (FC * PP) + 4 * q;   // + c*49 + bl
    #pragma unroll
    for (int b2 = 0; b2 < 4; b2++) {
        if (b2 < nb)
            ob[tid * PP + b2] = s_out[b2][tid];
    }
}

// ---------- Fallback (round-1 kernel) if workspace too small ----------
__global__ __launch_bounds__(256) void roi_align_fallback(
    const float* __restrict__ feat,
    const float* __restrict__ rois,
    float* __restrict__ out,
    int C, int H, int W, int N)
{
    int idx = blockIdx.x * blockDim.x + threadIdx.x;
    int total = N * C * PP;
    if (idx >= total) return;

    int pw = idx % POOLED;
    int ph = (idx / POOLED) % POOLED;
    int c  = (idx / PP) % C;
    int n  = idx / (PP * C);

    const float* r = rois + (size_t)n * 5;
    int   b  = (int)r[0];
    float x1 = r[1] * ROI_SCALE;
    float y1 = r[2] * ROI_SCALE;
    float bin_w = fmaxf(r[3] * ROI_SCALE - x1, 1.0f) / (float)POOLED;
    float bin_h = fmaxf(r[4] * ROI_SCALE - y1, 1.0f) / (float)POOLED;

    const float* fc = feat + ((size_t)b * C + c) * (size_t)(H * W);

    float acc = 0.0f;
    #pragma unroll
    for (int iy = 0; iy < 2; iy++) {
        float yy = y1 + ((float)(ph * 2 + iy) + 0.5f) * bin_h * 0.5f;
        bool  vy = (yy >= -1.0f) && (yy <= (float)H);
        float cy = fmaxf(yy, 0.0f);
        int   ylo = (int)floorf(cy);
        bool  ey = (ylo >= H - 1);
        ylo = min(ylo, H - 1);
        int   yhi = min(ylo + 1, H - 1);
        if (ey) cy = (float)ylo;
        float ly = cy - (float)ylo, hy = 1.0f - ly;

        #pragma unroll
        for (int ix = 0; ix < 2; ix++) {
            float xx = x1 + ((float)(pw * 2 + ix) + 0.5f) * bin_w * 0.5f;
            bool  vx = (xx >= -1.0f) && (xx <= (float)W);
            float cx = fmaxf(xx, 0.0f);
            int   xlo = (int)floorf(cx);
            bool  ex = (xlo >= W - 1);
            xlo = min(xlo, W - 1);
            int   xhi = min(xlo + 1, W - 1);
            if (ex) cx = (float)xlo;
            float lx = cx - (float)xlo, hx = 1.0f - lx;

            if (vy && vx) {
                float v11 = fc[(size_t)ylo * W + xlo];
                float v12 = fc[(size_t)ylo * W + xhi];
                float v21 = fc[(size_t)yhi * W + xlo];
                float v22 = fc[(size_t)yhi * W + xhi];
                acc += hy * (hx * v11 + lx * v12) + ly * (hx * v21 + lx * v22);
            }
        }
    }
    out[idx] = acc * 0.25f;
}

extern "C" void kernel_launch(void* const* d_in, const int* in_sizes, int n_in,
                              void* d_out, int out_size, void* d_ws, size_t ws_size,
                              hipStream_t stream) {
    const float* feat = (const float*)d_in[0];
    const float* rois = (const float*)d_in[1];
    float* out = (float*)d_out;

    const int N = in_sizes[1] / 5;
    const int B = in_sizes[0] / (FC * FHW);

    size_t need = (size_t)B * FHW * FC * sizeof(__half);
    if (ws_size >= need) {
        __half* f16 = (__half*)d_ws;
        transpose_f16<<<dim3(FHW / 32, FC / 64, B), dim3(32, 8), 0, stream>>>(feat, f16);
        roi_gather_f16<<<dim3(N, 13), 256, 0, stream>>>(f16, rois, out);
    } else {
        int total = N * FC * PP;
        roi_align_fallback<<<(total + 255) / 256, 256, 0, stream>>>(feat, rois, out, FC, FH, FW, N);
    }
}

// Round 6
// 80.279 us; speedup vs baseline: 1.5398x; 1.5398x over previous
//
#include <hip/hip_runtime.h>
#include <hip/hip_fp16.h>

#define POOLED 7
#define PP 49
#define ROI_SCALE 0.25f
#define FH 200
#define FW 304
#define FHW 60800
#define FC 256
#define RS 271           // s_out row stride (odd => conflict-free read-back)

// ---------- Pass 1: NCHW fp32 -> NHWC fp16 ----------
__global__ __launch_bounds__(256) void transpose_f16(
    const float* __restrict__ in, __half* __restrict__ out)
{
    __shared__ float tile[64][33];
    const int b   = blockIdx.z;
    const int hw0 = blockIdx.x * 32;
    const int c0  = blockIdx.y * 64;
    const int tx  = threadIdx.x;   // 0..31
    const int ty  = threadIdx.y;   // 0..7

    #pragma unroll
    for (int i = 0; i < 8; i++) {
        int c = c0 + ty + i * 8;
        tile[ty + i * 8][tx] = in[((size_t)b * FC + c) * FHW + hw0 + tx];
    }
    __syncthreads();
    #pragma unroll
    for (int i = 0; i < 4; i++) {
        int hwl = ty + i * 8;
        __half2 h = __floats2half2_rn(tile[2 * tx][hwl], tile[2 * tx + 1][hwl]);
        *reinterpret_cast<__half2*>(
            out + ((size_t)b * FHW + hwl + hw0) * FC + c0 + 2 * tx) = h;
    }
}

// load 8 consecutive fp16 channels (16 B) and widen
__device__ __forceinline__ void ld8(const __half* p, float o[8]) {
    uint4 u = *reinterpret_cast<const uint4*>(p);
    const __half2* h = reinterpret_cast<const __half2*>(&u);
    #pragma unroll
    for (int j = 0; j < 4; j++) {
        float2 f = __half22float2(h[j]);
        o[2 * j]     = f.x;
        o[2 * j + 1] = f.y;
    }
}

// ---------- Pass 2: one block (512 thr, 8 waves) per ROI.
// Wave w owns bins w, w+8, ... (49 bins total). Lane owns 8 channels (16B).
// Half-wave split: lanes<32 load the xlo pixel, lanes>=32 the xhi pixel
// -> 8 independent dwordx4 loads per bin. Output staged in LDS [bin][RS]
// with a small intra-row swizzle, then written fully coalesced.
__global__ __launch_bounds__(512) void roi_gather_f16(
    const __half* __restrict__ f,
    const float* __restrict__ rois,
    float* __restrict__ out)
{
    __shared__ float s_out[PP * RS];   // 53,116 B -> 3 blocks/CU

    const int n    = blockIdx.x;
    const int tid  = threadIdx.x;
    const int wave = tid >> 6;
    const int lane = tid & 63;
    const int hl   = lane & 31;
    const bool hiHalf = lane >= 32;

    const float* r = rois + (size_t)n * 5;
    const int   bi = (int)r[0];
    const float x1 = r[1] * ROI_SCALE;
    const float y1 = r[2] * ROI_SCALE;
    const float bin_w = fmaxf(r[3] * ROI_SCALE - x1, 1.0f) / (float)POOLED;
    const float bin_h = fmaxf(r[4] * ROI_SCALE - y1, 1.0f) / (float)POOLED;

    const __half* base = f + (size_t)bi * (FHW * FC) + 8 * hl;
    const int c0  = 8 * hl;
    const int swz = 2 * (hl >> 2);   // == 2*(c0>>5); keeps LDS stores <=2-way

    #pragma unroll 2
    for (int bin = wave; bin < PP; bin += 8) {
        const int ph = bin / 7;
        const int pw = bin - ph * 7;

        // y params for the bin's two y-samples
        int rowlo[2], rowhi[2];
        float why[2], wly[2];
        #pragma unroll
        for (int iy = 0; iy < 2; iy++) {
            float c = y1 + ((float)(2 * ph + iy) + 0.5f) * 0.5f * bin_h;
            float v = ((c >= -1.0f) && (c <= (float)FH)) ? 1.0f : 0.0f;
            c = fmaxf(c, 0.0f);
            int lo = (int)floorf(c);
            bool edge = (lo >= FH - 1);
            lo = min(lo, FH - 1);
            rowlo[iy] = lo * FW;
            rowhi[iy] = min(lo + 1, FH - 1) * FW;
            float ly = edge ? 0.0f : (c - (float)lo);
            why[iy] = v * (1.0f - ly);
            wly[iy] = v * ly;
        }
        // x params: per-half select lo/hi pixel and matching weight
        int   xoff[2];
        float wx[2];
        #pragma unroll
        for (int ix = 0; ix < 2; ix++) {
            float c = x1 + ((float)(2 * pw + ix) + 0.5f) * 0.5f * bin_w;
            float v = ((c >= -1.0f) && (c <= (float)FW)) ? 1.0f : 0.0f;
            c = fmaxf(c, 0.0f);
            int lo = (int)floorf(c);
            bool edge = (lo >= FW - 1);
            lo = min(lo, FW - 1);
            int hi = min(lo + 1, FW - 1);
            float lx = edge ? 0.0f : (c - (float)lo);
            xoff[ix] = hiHalf ? hi : lo;
            wx[ix]   = v * (hiHalf ? lx : (1.0f - lx));
        }

        float acc[8] = {0.f, 0.f, 0.f, 0.f, 0.f, 0.f, 0.f, 0.f};
        #pragma unroll
        for (int iy = 0; iy < 2; iy++) {
            #pragma unroll
            for (int ix = 0; ix < 2; ix++) {
                float vlo[8], vhi[8];
                ld8(base + ((rowlo[iy] + xoff[ix]) << 8), vlo);
                ld8(base + ((rowhi[iy] + xoff[ix]) << 8), vhi);
                float wlo = why[iy] * wx[ix];
                float whi = wly[iy] * wx[ix];
                #pragma unroll
                for (int k = 0; k < 8; k++)
                    acc[k] += wlo * vlo[k] + whi * vhi[k];
            }
        }

        // merge xlo/xhi halves: lane i += lane i^32
        #pragma unroll
        for (int k = 0; k < 8; k++)
            acc[k] += __shfl_xor(acc[k], 32, 64);

        if (!hiHalf) {
            float* so = s_out + bin * RS + c0 + swz;
            #pragma unroll
            for (int k = 0; k < 8; k++)
                so[k] = acc[k] * 0.25f;
        }
    }
    __syncthreads();

    // fully coalesced write: out[n][c][bin], consecutive tid -> consecutive addr
    float* ob = out + (size_t)n * (FC * PP);
    for (int i = tid; i < FC * PP; i += 512) {
        int c = i / PP;
        int b = i - c * PP;
        ob[i] = s_out[b * RS + c + 2 * (c >> 5)];
    }
}

// ---------- Fallback (round-1 kernel) if workspace too small ----------
__global__ __launch_bounds__(256) void roi_align_fallback(
    const float* __restrict__ feat,
    const float* __restrict__ rois,
    float* __restrict__ out,
    int C, int H, int W, int N)
{
    int idx = blockIdx.x * blockDim.x + threadIdx.x;
    int total = N * C * PP;
    if (idx >= total) return;

    int pw = idx % POOLED;
    int ph = (idx / POOLED) % POOLED;
    int c  = (idx / PP) % C;
    int n  = idx / (PP * C);

    const float* r = rois + (size_t)n * 5;
    int   b  = (int)r[0];
    float x1 = r[1] * ROI_SCALE;
    float y1 = r[2] * ROI_SCALE;
    float bin_w = fmaxf(r[3] * ROI_SCALE - x1, 1.0f) / (float)POOLED;
    float bin_h = fmaxf(r[4] * ROI_SCALE - y1, 1.0f) / (float)POOLED;

    const float* fc = feat + ((size_t)b * C + c) * (size_t)(H * W);

    float acc = 0.0f;
    #pragma unroll
    for (int iy = 0; iy < 2; iy++) {
        float yy = y1 + ((float)(ph * 2 + iy) + 0.5f) * bin_h * 0.5f;
        bool  vy = (yy >= -1.0f) && (yy <= (float)H);
        float cy = fmaxf(yy, 0.0f);
        int   ylo = (int)floorf(cy);
        bool  ey = (ylo >= H - 1);
        ylo = min(ylo, H - 1);
        int   yhi = min(ylo + 1, H - 1);
        if (ey) cy = (float)ylo;
        float ly = cy - (float)ylo, hy = 1.0f - ly;

        #pragma unroll
        for (int ix = 0; ix < 2; ix++) {
            float xx = x1 + ((float)(pw * 2 + ix) + 0.5f) * bin_w * 0.5f;
            bool  vx = (xx >= -1.0f) && (xx <= (float)W);
            float cx = fmaxf(xx, 0.0f);
            int   xlo = (int)floorf(cx);
            bool  ex = (xlo >= W - 1);
            xlo = min(xlo, W - 1);
            int   xhi = min(xlo + 1, W - 1);
            if (ex) cx = (float)xlo;
            float lx = cx - (float)xlo, hx = 1.0f - lx;

            if (vy && vx) {
                float v11 = fc[(size_t)ylo * W + xlo];
                float v12 = fc[(size_t)ylo * W + xhi];
                float v21 = fc[(size_t)yhi * W + xlo];
                float v22 = fc[(size_t)yhi * W + xhi];
                acc += hy * (hx * v11 + lx * v12) + ly * (hx * v21 + lx * v22);
            }
        }
    }
    out[idx] = acc * 0.25f;
}

extern "C" void kernel_launch(void* const* d_in, const int* in_sizes, int n_in,
                              void* d_out, int out_size, void* d_ws, size_t ws_size,
                              hipStream_t stream) {
    const float* feat = (const float*)d_in[0];
    const float* rois = (const float*)d_in[1];
    float* out = (float*)d_out;

    const int N = in_sizes[1] / 5;
    const int B = in_sizes[0] / (FC * FHW);

    size_t need = (size_t)B * FHW * FC * sizeof(__half);
    if (ws_size >= need) {
        __half* f16 = (__half*)d_ws;
        transpose_f16<<<dim3(FHW / 32, FC / 64, B), dim3(32, 8), 0, stream>>>(feat, f16);
        roi_gather_f16<<<N, 512, 0, stream>>>(f16, rois, out);
    } else {
        int total = N * FC * PP;
        roi_align_fallback<<<(total + 255) / 256, 256, 0, stream>>>(feat, rois, out, FC, FH, FW, N);
    }
}

// Round 7
// 79.580 us; speedup vs baseline: 1.5533x; 1.0088x over previous
//
#include <hip/hip_runtime.h>
#include <hip/hip_fp16.h>

#define POOLED 7
#define PP 49
#define ROI_SCALE 0.25f
#define FH 200
#define FW 304
#define FHW 60800
#define FC 256
#define RS 271           // s_out row stride (odd => conflict-free read-back)

// ---------- Pass 0: spatial sort of ROIs (single block, bitonic, deterministic) ----
// key = batch(1b) | morton7x7(y,x)(14b) | roi_idx(10b). Sorting groups spatially
// adjacent ROIs; gather maps contiguous sorted runs to the same XCD for L2 locality.
__global__ __launch_bounds__(1024) void sort_rois(
    const float* __restrict__ rois, int N, unsigned* __restrict__ perm)
{
    __shared__ unsigned key[1024];
    const int t = threadIdx.x;
    unsigned v = 0xFFFFFFFFu;
    if (t < N) {
        const float* r = rois + (size_t)t * 5;
        int b = (int)r[0];
        float yc = (r[2] + r[4]) * (0.5f * ROI_SCALE);   // feature-space center
        float xc = (r[1] + r[3]) * (0.5f * ROI_SCALE);
        int yq = min(127, max(0, (int)yc >> 1));
        int xq = min(127, max(0, (int)xc >> 2));
        unsigned m = 0;
        #pragma unroll
        for (int i = 0; i < 7; i++)
            m |= (((unsigned)((yq >> i) & 1)) << (2 * i + 1)) |
                 (((unsigned)((xq >> i) & 1)) << (2 * i));
        v = ((unsigned)b << 25) | (m << 10) | (unsigned)t;
    }
    key[t] = v;
    __syncthreads();
    for (int k = 2; k <= 1024; k <<= 1) {
        for (int j = k >> 1; j > 0; j >>= 1) {
            int p = t ^ j;
            if (p > t) {
                unsigned a = key[t], b2 = key[p];
                bool sw = ((t & k) == 0) ? (a > b2) : (a < b2);
                if (sw) { key[t] = b2; key[p] = a; }
            }
            __syncthreads();
        }
    }
    if (t < N) perm[t] = key[t];
}

// ---------- Pass 1: NCHW fp32 -> NHWC fp16 ----------
__global__ __launch_bounds__(256) void transpose_f16(
    const float* __restrict__ in, __half* __restrict__ out)
{
    __shared__ float tile[64][33];
    const int b   = blockIdx.z;
    const int hw0 = blockIdx.x * 32;
    const int c0  = blockIdx.y * 64;
    const int tx  = threadIdx.x;   // 0..31
    const int ty  = threadIdx.y;   // 0..7

    #pragma unroll
    for (int i = 0; i < 8; i++) {
        int c = c0 + ty + i * 8;
        tile[ty + i * 8][tx] = in[((size_t)b * FC + c) * FHW + hw0 + tx];
    }
    __syncthreads();
    #pragma unroll
    for (int i = 0; i < 4; i++) {
        int hwl = ty + i * 8;
        __half2 h = __floats2half2_rn(tile[2 * tx][hwl], tile[2 * tx + 1][hwl]);
        *reinterpret_cast<__half2*>(
            out + ((size_t)b * FHW + hwl + hw0) * FC + c0 + 2 * tx) = h;
    }
}

// ---------- Pass 2: one block (512 thr, 8 waves) per ROI. ----------
// Wave w owns bins w, w+8, ... Lane owns 8 channels (16B). Half-wave split:
// lanes<32 load the xlo pixel, lanes>=32 the xhi pixel. All 8 pixel loads of a
// bin are issued as one batch (uint4 u[8]) before any FMA. Block -> ROI via
// sorted perm with bijective XCD chunking (each XCD gets a contiguous sorted run).
__global__ __launch_bounds__(512, 6) void roi_gather_f16(
    const __half* __restrict__ f,
    const float* __restrict__ rois,
    const unsigned* __restrict__ perm,
    float* __restrict__ out,
    int N, int useperm)
{
    __shared__ float s_out[PP * RS];   // 53,116 B -> 3 blocks/CU

    const int bid = blockIdx.x;
    int n;
    if (useperm) {
        int xcd = bid & 7, pos = bid >> 3;
        int q = N >> 3, rr = N & 7;
        int sidx = (xcd < rr) ? xcd * (q + 1) + pos
                              : rr * (q + 1) + (xcd - rr) * q + pos;
        n = (int)(perm[sidx] & 1023u);
    } else {
        n = bid;
    }

    const int tid  = threadIdx.x;
    const int wave = tid >> 6;
    const int lane = tid & 63;
    const int hl   = lane & 31;
    const bool hiHalf = lane >= 32;

    const float* r = rois + (size_t)n * 5;
    const int   bi = (int)r[0];
    const float x1 = r[1] * ROI_SCALE;
    const float y1 = r[2] * ROI_SCALE;
    const float bin_w = fmaxf(r[3] * ROI_SCALE - x1, 1.0f) / (float)POOLED;
    const float bin_h = fmaxf(r[4] * ROI_SCALE - y1, 1.0f) / (float)POOLED;

    const __half* base = f + (size_t)bi * (FHW * FC) + 8 * hl;
    const int c0  = 8 * hl;
    const int swz = 2 * (hl >> 2);   // == 2*(c0>>5); keeps LDS stores <=2-way

    for (int bin = wave; bin < PP; bin += 8) {
        const int ph = bin / 7;
        const int pw = bin - ph * 7;

        // y params for the bin's two y-samples
        int rowlo[2], rowhi[2];
        float why[2], wly[2];
        #pragma unroll
        for (int iy = 0; iy < 2; iy++) {
            float c = y1 + ((float)(2 * ph + iy) + 0.5f) * 0.5f * bin_h;
            float v = ((c >= -1.0f) && (c <= (float)FH)) ? 1.0f : 0.0f;
            c = fmaxf(c, 0.0f);
            int lo = (int)floorf(c);
            bool edge = (lo >= FH - 1);
            lo = min(lo, FH - 1);
            rowlo[iy] = lo * FW;
            rowhi[iy] = min(lo + 1, FH - 1) * FW;
            float ly = edge ? 0.0f : (c - (float)lo);
            why[iy] = v * (1.0f - ly);
            wly[iy] = v * ly;
        }
        // x params: per-half select lo/hi pixel and matching weight
        int   xoff[2];
        float wx[2];
        #pragma unroll
        for (int ix = 0; ix < 2; ix++) {
            float c = x1 + ((float)(2 * pw + ix) + 0.5f) * 0.5f * bin_w;
            float v = ((c >= -1.0f) && (c <= (float)FW)) ? 1.0f : 0.0f;
            c = fmaxf(c, 0.0f);
            int lo = (int)floorf(c);
            bool edge = (lo >= FW - 1);
            lo = min(lo, FW - 1);
            int hi = min(lo + 1, FW - 1);
            float lx = edge ? 0.0f : (c - (float)lo);
            xoff[ix] = hiHalf ? hi : lo;
            wx[ix]   = v * (hiHalf ? lx : (1.0f - lx));
        }

        // issue all 8 pixel loads before any use
        uint4 u[8];
        #pragma unroll
        for (int s = 0; s < 4; s++) {
            int iy = s >> 1, ix = s & 1;
            int px = xoff[ix];
            u[2 * s]     = *reinterpret_cast<const uint4*>(base + ((rowlo[iy] + px) << 8));
            u[2 * s + 1] = *reinterpret_cast<const uint4*>(base + ((rowhi[iy] + px) << 8));
        }

        float acc[8] = {0.f, 0.f, 0.f, 0.f, 0.f, 0.f, 0.f, 0.f};
        #pragma unroll
        for (int s = 0; s < 4; s++) {
            int iy = s >> 1, ix = s & 1;
            float wlo = why[iy] * wx[ix];
            float whi = wly[iy] * wx[ix];
            const __half2* hlo = reinterpret_cast<const __half2*>(&u[2 * s]);
            const __half2* hhi = reinterpret_cast<const __half2*>(&u[2 * s + 1]);
            #pragma unroll
            for (int j = 0; j < 4; j++) {
                float2 flo = __half22float2(hlo[j]);
                float2 fhi = __half22float2(hhi[j]);
                acc[2 * j]     += wlo * flo.x + whi * fhi.x;
                acc[2 * j + 1] += wlo * flo.y + whi * fhi.y;
            }
        }

        // merge xlo/xhi halves: lane i += lane i^32
        #pragma unroll
        for (int k = 0; k < 8; k++)
            acc[k] += __shfl_xor(acc[k], 32, 64);

        if (!hiHalf) {
            float* so = s_out + bin * RS + c0 + swz;
            #pragma unroll
            for (int k = 0; k < 8; k++)
                so[k] = acc[k] * 0.25f;
        }
    }
    __syncthreads();

    // fully coalesced write: out[n][c][bin], consecutive tid -> consecutive addr
    float* ob = out + (size_t)n * (FC * PP);
    for (int i = tid; i < FC * PP; i += 512) {
        int c = i / PP;
        int b = i - c * PP;
        ob[i] = s_out[b * RS + c + 2 * (c >> 5)];
    }
}

// ---------- Fallback (round-1 kernel) if workspace too small ----------
__global__ __launch_bounds__(256) void roi_align_fallback(
    const float* __restrict__ feat,
    const float* __restrict__ rois,
    float* __restrict__ out,
    int C, int H, int W, int N)
{
    int idx = blockIdx.x * blockDim.x + threadIdx.x;
    int total = N * C * PP;
    if (idx >= total) return;

    int pw = idx % POOLED;
    int ph = (idx / POOLED) % POOLED;
    int c  = (idx / PP) % C;
    int n  = idx / (PP * C);

    const float* r = rois + (size_t)n * 5;
    int   b  = (int)r[0];
    float x1 = r[1] * ROI_SCALE;
    float y1 = r[2] * ROI_SCALE;
    float bin_w = fmaxf(r[3] * ROI_SCALE - x1, 1.0f) / (float)POOLED;
    float bin_h = fmaxf(r[4] * ROI_SCALE - y1, 1.0f) / (float)POOLED;

    const float* fc = feat + ((size_t)b * C + c) * (size_t)(H * W);

    float acc = 0.0f;
    #pragma unroll
    for (int iy = 0; iy < 2; iy++) {
        float yy = y1 + ((float)(ph * 2 + iy) + 0.5f) * bin_h * 0.5f;
        bool  vy = (yy >= -1.0f) && (yy <= (float)H);
        float cy = fmaxf(yy, 0.0f);
        int   ylo = (int)floorf(cy);
        bool  ey = (ylo >= H - 1);
        ylo = min(ylo, H - 1);
        int   yhi = min(ylo + 1, H - 1);
        if (ey) cy = (float)ylo;
        float ly = cy - (float)ylo, hy = 1.0f - ly;

        #pragma unroll
        for (int ix = 0; ix < 2; ix++) {
            float xx = x1 + ((float)(pw * 2 + ix) + 0.5f) * bin_w * 0.5f;
            bool  vx = (xx >= -1.0f) && (xx <= (float)W);
            float cx = fmaxf(xx, 0.0f);
            int   xlo = (int)floorf(cx);
            bool  ex = (xlo >= W - 1);
            xlo = min(xlo, W - 1);
            int   xhi = min(xlo + 1, W - 1);
            if (ex) cx = (float)xlo;
            float lx = cx - (float)xlo, hx = 1.0f - lx;

            if (vy && vx) {
                float v11 = fc[(size_t)ylo * W + xlo];
                float v12 = fc[(size_t)ylo * W + xhi];
                float v21 = fc[(size_t)yhi * W + xlo];
                float v22 = fc[(size_t)yhi * W + xhi];
                acc += hy * (hx * v11 + lx * v12) + ly * (hx * v21 + lx * v22);
            }
        }
    }
    out[idx] = acc * 0.25f;
}

extern "C" void kernel_launch(void* const* d_in, const int* in_sizes, int n_in,
                              void* d_out, int out_size, void* d_ws, size_t ws_size,
                              hipStream_t stream) {
    const float* feat = (const float*)d_in[0];
    const float* rois = (const float*)d_in[1];
    float* out = (float*)d_out;

    const int N = in_sizes[1] / 5;
    const int B = in_sizes[0] / (FC * FHW);

    const size_t featBytes = (size_t)B * FHW * FC * sizeof(__half);
    const size_t permOff   = (featBytes + 255) & ~(size_t)255;
    const size_t need      = permOff + 1024 * sizeof(unsigned);

    if (ws_size >= need) {
        __half*   f16  = (__half*)d_ws;
        unsigned* perm = (unsigned*)((char*)d_ws + permOff);
        int useperm = (N <= 1024) ? 1 : 0;
        if (useperm)
            sort_rois<<<1, 1024, 0, stream>>>(rois, N, perm);
        transpose_f16<<<dim3(FHW / 32, FC / 64, B), dim3(32, 8), 0, stream>>>(feat, f16);
        roi_gather_f16<<<N, 512, 0, stream>>>(f16, rois, perm, out, N, useperm);
    } else {
        int total = N * FC * PP;
        roi_align_fallback<<<(total + 255) / 256, 256, 0, stream>>>(feat, rois, out, FC, FH, FW, N);
    }
}